// Round 2
// baseline (445.014 us; speedup 1.0000x reference)
//
#include <hip/hip_runtime.h>

// Problem constants (from reference)
#define CC 9605
#define BB 2048
#define LL 8
#define NSLOT 41          // 10 float4-groups + 1 head/tail extra per thread
#define CAND_MAX 2048
#define NEGF (-1e30f)

// order-preserving float->uint encode: larger float <=> larger uint
__device__ __forceinline__ unsigned enc_f(float f) {
  unsigned u = __float_as_uint(f);
  return (u & 0x80000000u) ? ~u : (u | 0x80000000u);
}
__device__ __forceinline__ float dec_u(unsigned e) {
  unsigned u = (e & 0x80000000u) ? (e & 0x7fffffffu) : ~e;
  return __uint_as_float(u);
}
__device__ __forceinline__ float sigm(float z) {
  return 1.0f / (1.0f + __expf(-z));
}

// Compact wl_masks [L, C] into list of (col<<8 | label_bitmask).
// The harness may hand us the bool array as u8 / int32 / f32 / bf16 —
// sniff the dtype from byte signatures in the first L*C bytes (safe to read
// under every layout; disjoint signatures):
//   u8  : byte==1 at offsets %4 != 0
//   i32 : byte==1 only at offsets %4 == 0
//   f32 : 1.0f = 00 00 80 3f -> 0x3f at %4==3, never byte==1
//   bf16: 1.0  = 80 3f       -> 0x3f at odd offsets incl %4==1
__global__ void wl_setup_kernel(const unsigned char* __restrict__ wl,
                                unsigned* __restrict__ wsu) {
  __shared__ unsigned cnt;
  __shared__ unsigned flags;
  __shared__ int s_dtype;
  __shared__ unsigned buf[2048];
  const int tid = threadIdx.x;
  if (tid == 0) { cnt = 0u; flags = 0u; }
  __syncthreads();
  unsigned f = 0u;
  for (int i = tid; i < LL * CC; i += 256) {
    unsigned b = wl[i];
    if (b == 1u) { f |= 2u; if ((i & 3) != 0) f |= 1u; }
    if (b == 0x3fu) { f |= 8u; if ((i & 3) == 1) f |= 4u; }
  }
  atomicOr(&flags, f);
  __syncthreads();
  if (tid == 0) {
    unsigned g = flags;
    int dt;                       // 0=u8 1=i32 2=f32 3=bf16
    if (g & 1u) dt = 0;
    else if (g & 4u) dt = 3;
    else if (g & 2u) dt = 1;
    else if (g & 8u) dt = 2;
    else dt = 0;                  // all-zero masks; interpretation irrelevant
    s_dtype = dt;
  }
  __syncthreads();
  const int dt = s_dtype;
  const int* wl32 = (const int*)wl;
  const float* wlf = (const float*)wl;
  const unsigned short* wlh = (const unsigned short*)wl;
  for (int c = tid; c < CC; c += 256) {
    unsigned m = 0u;
#pragma unroll
    for (int l = 0; l < LL; ++l) {
      int j = l * CC + c;
      bool on;
      if (dt == 0) on = (wl[j] != 0);
      else if (dt == 1) on = (wl32[j] != 0);
      else if (dt == 2) on = (wlf[j] != 0.0f);
      else on = (wlh[j] != 0);
      if (on) m |= (1u << l);
    }
    if (m) {
      unsigned p = atomicAdd(&cnt, 1u);
      if (p < 2048u) buf[p] = ((unsigned)c << 8) | m;
    }
  }
  __syncthreads();
  unsigned n = cnt;
  if (n > 2048u) n = 2048u;
  if (tid == 0) wsu[0] = n;
  for (unsigned i = tid; i < n; i += 256u) wsu[4 + i] = buf[i];
}

__global__ __launch_bounds__(256) void loss_kernel(
    const float* __restrict__ x, const float* __restrict__ y,
    const unsigned* __restrict__ wsu, float* __restrict__ out) {
  __shared__ unsigned sh_hist[256];
  __shared__ unsigned sh_cand[CAND_MAX];
  __shared__ unsigned sh_redU[4];
  __shared__ unsigned sh_sel[2];
  __shared__ float sh_wl[4][12];

  const int tid = threadIdx.x;
  const int lane = tid & 63;
  const int wid = tid >> 6;
  const int b = blockIdx.x;
  const long long base = (long long)b * CC;

  // ---- 1. stream row (coalesced float4, per-row alignment fixup), encode ----
  unsigned enc[NSLOT];
  const int soff = (4 - (b & 3)) & 3;          // base%4 == b%4 (9605 % 4 == 1)
  const int ngroups = (CC - soff) >> 2;        // 2400 or 2401
  const int tailn = CC - soff - (ngroups << 2);
  const int m_extra = soff + tailn;            // <= 6 scalar leftovers
  const float4* vp = (const float4*)(x + base + soff);  // 16B aligned
#pragma unroll
  for (int i = 0; i < 10; ++i) {
    int g = tid + (i << 8);
    if (g < ngroups) {
      float4 v = vp[g];
      enc[4 * i + 0] = enc_f(v.x);
      enc[4 * i + 1] = enc_f(v.y);
      enc[4 * i + 2] = enc_f(v.z);
      enc[4 * i + 3] = enc_f(v.w);
    } else {
      enc[4 * i + 0] = 0u; enc[4 * i + 1] = 0u;
      enc[4 * i + 2] = 0u; enc[4 * i + 3] = 0u;  // pad: below any real enc
    }
  }
  if (tid < m_extra) {
    int col = (tid < soff) ? tid : (soff + (ngroups << 2) + (tid - soff));
    enc[40] = enc_f(x[base + col]);
  } else {
    enc[40] = 0u;
  }

  unsigned mx = 0u;
#pragma unroll
  for (int i = 0; i < NSLOT; ++i) mx = max(mx, enc[i]);

  // block count of enc >= T (uniform result on all threads)
  auto blk_count = [&](unsigned T) -> unsigned {
    unsigned cnt = 0u;
#pragma unroll
    for (int i = 0; i < NSLOT; ++i) cnt += (enc[i] >= T) ? 1u : 0u;
#pragma unroll
    for (int off = 32; off >= 1; off >>= 1) cnt += __shfl_xor(cnt, off, 64);
    __syncthreads();  // protect sh_redU from previous use
    if (lane == 0) sh_redU[wid] = cnt;
    __syncthreads();
    return sh_redU[0] + sh_redU[1] + sh_redU[2] + sh_redU[3];
  };

  // ---- 2. block max ----
#pragma unroll
  for (int off = 32; off >= 1; off >>= 1) mx = max(mx, __shfl_xor(mx, off, 64));
  if (lane == 0) sh_redU[wid] = mx;
  __syncthreads();
  const unsigned Emax =
      max(max(sh_redU[0], sh_redU[1]), max(sh_redU[2], sh_redU[3]));

  // ---- 3. find threshold window containing rank 11 (exact, robust) ----
  unsigned E11 = 0u;
  bool done = false;
  unsigned c = blk_count(Emax);
  if (c >= 11u) { E11 = Emax; done = true; }  // >=11 ties at max
  unsigned lo = Emax, hi = Emax;
  if (!done) {
    const unsigned STEP = 1u << 23;  // ~one exponent step for positives
    while (true) {
      hi = lo;
      lo = (lo > STEP) ? (lo - STEP) : 1u;
      c = blk_count(lo);
      if (c >= 11u) break;
      if (lo == 1u) break;  // unreachable for C>=11 real values
    }
    // shrink candidate set if pathologically large; tie-collapse => direct answer
    while (c > CAND_MAX) {
      if (hi - lo <= 1u) { E11 = lo; done = true; break; }
      unsigned mid = lo + ((hi - lo) >> 1);
      unsigned cm = blk_count(mid);
      if (cm >= 11u) { lo = mid; c = cm; } else { hi = mid; }
    }
  }

  // ---- 4. compact candidates (enc >= lo) into LDS, radix-select rank 11 ----
  if (!done) {
    __syncthreads();
    if (tid == 0) sh_sel[0] = 0u;
    __syncthreads();
#pragma unroll
    for (int i = 0; i < NSLOT; ++i) {
      bool pr = (enc[i] >= lo);
      unsigned long long bal = __ballot(pr);
      if (bal) {
        unsigned wcnt = (unsigned)__popcll(bal);
        unsigned basep = 0u;
        if (lane == 0) basep = atomicAdd(&sh_sel[0], wcnt);
        basep = __shfl(basep, 0, 64);
        if (pr) {
          unsigned posn = basep + (unsigned)__popcll(bal & ((1ull << lane) - 1ull));
          sh_cand[posn] = enc[i];
        }
      }
    }
    __syncthreads();

    unsigned prefix = 0u, r = 11u;
    for (int p = 3; p >= 0; --p) {
      sh_hist[tid] = 0u;
      __syncthreads();
      for (unsigned i = tid; i < c; i += 256u) {
        unsigned e = sh_cand[i];
        bool match =
            (p == 3) || ((e >> ((p + 1) * 8)) == (prefix >> ((p + 1) * 8)));
        if (match) atomicAdd(&sh_hist[(e >> (p * 8)) & 255u], 1u);
      }
      __syncthreads();
      if (wid == 0) {
        unsigned b0 = sh_hist[4 * lane + 0], b1 = sh_hist[4 * lane + 1];
        unsigned b2 = sh_hist[4 * lane + 2], b3 = sh_hist[4 * lane + 3];
        unsigned s = b0 + b1 + b2 + b3;
        unsigned t = s;
#pragma unroll
        for (int off = 1; off < 64; off <<= 1) {
          unsigned v = __shfl_down(t, off, 64);
          if (lane + off < 64) t += v;
        }
        unsigned above = t - s;  // count over lanes > L (higher digits)
        unsigned suf3 = above + b3, suf2 = suf3 + b2, suf1 = suf2 + b1,
                 suf0 = suf1 + b0;
        if (suf0 >= r && suf1 < r) { sh_sel[0] = 4u * lane + 0u; sh_sel[1] = r - suf1; }
        if (suf1 >= r && suf2 < r) { sh_sel[0] = 4u * lane + 1u; sh_sel[1] = r - suf2; }
        if (suf2 >= r && suf3 < r) { sh_sel[0] = 4u * lane + 2u; sh_sel[1] = r - suf3; }
        if (suf3 >= r && above < r){ sh_sel[0] = 4u * lane + 3u; sh_sel[1] = r - above; }
      }
      __syncthreads();
      prefix |= sh_sel[0] << (p * 8);
      r = sh_sel[1];
    }
    E11 = prefix;
  }

  // ---- 5. whitelist gather: per-label max, union max, has_pos ----
  __syncthreads();
  const unsigned nu = wsu[0];
  const unsigned* ents = wsu + 4;
  float lm[8];
#pragma unroll
  for (int l = 0; l < 8; ++l) lm[l] = NEGF;
  float um = NEGF;
  unsigned present = 0u, posm = 0u;
  for (unsigned e = tid; e < nu; e += 256u) {
    unsigned ent = ents[e];
    unsigned ccol = ent >> 8;
    unsigned mk = ent & 255u;
    float xv = x[base + (long long)ccol];
    float yv = y[base + (long long)ccol];
    present |= mk;
    if (yv > 0.0f) posm |= mk;
    um = fmaxf(um, xv);
#pragma unroll
    for (int l = 0; l < 8; ++l)
      if ((mk >> l) & 1u) lm[l] = fmaxf(lm[l], xv);
  }
#pragma unroll
  for (int off = 32; off >= 1; off >>= 1) {
    um = fmaxf(um, __shfl_xor(um, off, 64));
    present |= __shfl_xor(present, off, 64);
    posm |= __shfl_xor(posm, off, 64);
#pragma unroll
    for (int l = 0; l < 8; ++l) lm[l] = fmaxf(lm[l], __shfl_xor(lm[l], off, 64));
  }
  if (lane == 0) {
#pragma unroll
    for (int l = 0; l < 8; ++l) sh_wl[wid][l] = lm[l];
    sh_wl[wid][8] = um;
    sh_wl[wid][9] = __uint_as_float(present);
    sh_wl[wid][10] = __uint_as_float(posm);
  }
  __syncthreads();

  // ---- 6. epilogue on thread 0 ----
  if (tid == 0) {
    float LM[8], UM = NEGF;
    unsigned PR = 0u, PO = 0u;
#pragma unroll
    for (int l = 0; l < 8; ++l) LM[l] = NEGF;
    for (int w = 0; w < 4; ++w) {
#pragma unroll
      for (int l = 0; l < 8; ++l) LM[l] = fmaxf(LM[l], sh_wl[w][l]);
      UM = fmaxf(UM, sh_wl[w][8]);
      PR |= __float_as_uint(sh_wl[w][9]);
      PO |= __float_as_uint(sh_wl[w][10]);
    }
    float x11 = dec_u(E11);
    float thres = fmaxf(sigm(x11), 0.5f);
    float cmax = NEGF, imax = NEGF;
#pragma unroll
    for (int l = 0; l < 8; ++l) {
      float ml = ((PR >> l) & 1u) ? sigm(LM[l]) : NEGF;
      if ((PO >> l) & 1u) cmax = fmaxf(cmax, ml);
      else imax = fmaxf(imax, ml);
    }
    bool anyc = (PO != 0u);
    bool anyi = (PO != 255u);  // L == 8 labels, all whitelists non-empty
    float unionmax = (nu > 0u) ? sigm(UM) : NEGF;
    float x1 = anyc ? cmax : thres;
    float x2 = anyc ? (anyi ? fmaxf(imax, thres) : thres) : unionmax;
    float coef = anyc ? 1.0f : 0.5f;
    float dd = x2 - x1 + 0.1f;
    float rank = ((dd > 0.0f) ? 2.0f : 1.0f) * sigm(10.0f * dd);
    atomicAdd(out, coef * rank * (1.0f / (float)BB));
  }
}

extern "C" void kernel_launch(void* const* d_in, const int* in_sizes, int n_in,
                              void* d_out, int out_size, void* d_ws,
                              size_t ws_size, hipStream_t stream) {
  const float* x = (const float*)d_in[0];
  const float* y = (const float*)d_in[1];
  // d_in[2] (y_neg) is faithfully ignored — it never affects the loss.
  const unsigned char* wl = (const unsigned char*)d_in[3];
  float* out = (float*)d_out;
  unsigned* wsu = (unsigned*)d_ws;

  hipMemsetAsync(d_out, 0, sizeof(float), stream);  // harness poisons 0xAA
  wl_setup_kernel<<<1, 256, 0, stream>>>(wl, wsu);
  loss_kernel<<<BB, 256, 0, stream>>>(x, y, wsu, out);
}

// Round 3
// 236.462 us; speedup vs baseline: 1.8820x; 1.8820x over previous
//
#include <hip/hip_runtime.h>

// Problem constants (from reference)
#define CC 9605
#define BB 2048
#define LL 8
#define NSLOT 41          // 10 float4-groups + 1 head/tail extra per thread
#define CAND_MAX 2048
#define NEGF (-1e30f)

// d_ws layout (unsigned words):
//   wsu[0] = entry count (atomic)
//   wsu[1] = dtype sniff flags (atomic OR)
//   wsu[4 .. 4+2048) = whitelist entries (col<<8 | mask)
//   byte offset 16384: float partials[BB]
#define WS_PARTIALS_OFF 16384

// order-preserving float->uint encode: larger float <=> larger uint
__device__ __forceinline__ unsigned enc_f(float f) {
  unsigned u = __float_as_uint(f);
  return (u & 0x80000000u) ? ~u : (u | 0x80000000u);
}
__device__ __forceinline__ float dec_u(unsigned e) {
  unsigned u = (e & 0x80000000u) ? (e & 0x7fffffffu) : ~e;
  return __uint_as_float(u);
}
__device__ __forceinline__ float sigm(float z) {
  return 1.0f / (1.0f + __expf(-z));
}

// ---- dtype sniff: byte signatures over the raw wl buffer ----
//   u8  : byte==1 at offsets %4 != 0        -> flag 1 (and 2)
//   i32 : byte==1 only at offsets %4 == 0   -> flag 2
//   f32 : 0x3f at %4==3, never byte==1      -> flag 8
//   bf16: 0x3f at odd offsets incl %4==1    -> flag 4 (and 8)
__global__ void wl_sniff(const unsigned char* __restrict__ wl,
                         unsigned* __restrict__ wsu) {
  const int stride = gridDim.x * blockDim.x;
  unsigned f = 0u;
  for (int j = blockIdx.x * blockDim.x + threadIdx.x; j < LL * CC; j += stride) {
    unsigned b = wl[j];
    if (b == 1u)    { f |= 2u; if ((j & 3) != 0) f |= 1u; }
    if (b == 0x3fu) { f |= 8u; if ((j & 3) == 1) f |= 4u; }
  }
#pragma unroll
  for (int off = 32; off >= 1; off >>= 1) f |= __shfl_xor(f, off, 64);
  if ((threadIdx.x & 63) == 0 && f) atomicOr(&wsu[1], f);
}

__global__ void wl_compact(const unsigned char* __restrict__ wl,
                           unsigned* __restrict__ wsu) {
  const int tid = threadIdx.x;
  const int lane = tid & 63;
  const int c = blockIdx.x * 256 + tid;
  const unsigned g = wsu[1];
  const int dt = (g & 1u) ? 0 : (g & 4u) ? 3 : (g & 2u) ? 1 : (g & 8u) ? 2 : 0;
  const int* wl32 = (const int*)wl;
  const float* wlf = (const float*)wl;
  const unsigned short* wlh = (const unsigned short*)wl;
  unsigned m = 0u;
  if (c < CC) {
#pragma unroll
    for (int l = 0; l < LL; ++l) {
      int j = l * CC + c;
      bool on;
      if (dt == 0) on = (wl[j] != 0);
      else if (dt == 1) on = (wl32[j] != 0);
      else if (dt == 2) on = (wlf[j] != 0.0f);
      else on = (wlh[j] != 0);
      if (on) m |= (1u << l);
    }
  }
  unsigned long long bal = __ballot(m != 0u);
  if (bal) {
    unsigned wcnt = (unsigned)__popcll(bal);
    unsigned basep = 0u;
    if (lane == 0) basep = atomicAdd(&wsu[0], wcnt);
    basep = __shfl(basep, 0, 64);
    if (m) {
      unsigned pos = basep + (unsigned)__popcll(bal & ((1ull << lane) - 1ull));
      if (pos < 2048u) wsu[4 + pos] = ((unsigned)c << 8) | m;
    }
  }
}

__global__ __launch_bounds__(256) void loss_kernel(
    const float* __restrict__ x, const float* __restrict__ y,
    const unsigned* __restrict__ wsu, float* __restrict__ partials) {
  __shared__ unsigned sh_hist[256];
  __shared__ unsigned sh_cand[CAND_MAX];
  __shared__ unsigned sh_redU[4];
  __shared__ unsigned sh_sel[2];
  __shared__ float sh_wl[4][12];

  const int tid = threadIdx.x;
  const int lane = tid & 63;
  const int wid = tid >> 6;
  const int b = blockIdx.x;
  const long long base = (long long)b * CC;

  // ---- 1. stream row (coalesced float4, per-row alignment fixup), encode ----
  unsigned enc[NSLOT];
  const int soff = (4 - (b & 3)) & 3;          // base%4 == b%4 (9605 % 4 == 1)
  const int ngroups = (CC - soff) >> 2;        // 2400 or 2401
  const int tailn = CC - soff - (ngroups << 2);
  const int m_extra = soff + tailn;            // <= 6 scalar leftovers
  const float4* vp = (const float4*)(x + base + soff);  // 16B aligned
#pragma unroll
  for (int i = 0; i < 10; ++i) {
    int g = tid + (i << 8);
    if (g < ngroups) {
      float4 v = vp[g];
      enc[4 * i + 0] = enc_f(v.x);
      enc[4 * i + 1] = enc_f(v.y);
      enc[4 * i + 2] = enc_f(v.z);
      enc[4 * i + 3] = enc_f(v.w);
    } else {
      enc[4 * i + 0] = 0u; enc[4 * i + 1] = 0u;
      enc[4 * i + 2] = 0u; enc[4 * i + 3] = 0u;  // pad: below any real enc
    }
  }
  if (tid < m_extra) {
    int col = (tid < soff) ? tid : (soff + (ngroups << 2) + (tid - soff));
    enc[40] = enc_f(x[base + col]);
  } else {
    enc[40] = 0u;
  }

  unsigned mx = 0u;
#pragma unroll
  for (int i = 0; i < NSLOT; ++i) mx = max(mx, enc[i]);

  // block count of enc >= T (uniform result on all threads)
  auto blk_count = [&](unsigned T) -> unsigned {
    unsigned cnt = 0u;
#pragma unroll
    for (int i = 0; i < NSLOT; ++i) cnt += (enc[i] >= T) ? 1u : 0u;
#pragma unroll
    for (int off = 32; off >= 1; off >>= 1) cnt += __shfl_xor(cnt, off, 64);
    __syncthreads();  // protect sh_redU from previous use
    if (lane == 0) sh_redU[wid] = cnt;
    __syncthreads();
    return sh_redU[0] + sh_redU[1] + sh_redU[2] + sh_redU[3];
  };

  // ---- 2. block max ----
#pragma unroll
  for (int off = 32; off >= 1; off >>= 1) mx = max(mx, __shfl_xor(mx, off, 64));
  if (lane == 0) sh_redU[wid] = mx;
  __syncthreads();
  const unsigned Emax =
      max(max(sh_redU[0], sh_redU[1]), max(sh_redU[2], sh_redU[3]));

  // ---- 3. find threshold window containing rank 11 (exact, robust) ----
  unsigned E11 = 0u;
  bool done = false;
  unsigned c = blk_count(Emax);
  if (c >= 11u) { E11 = Emax; done = true; }  // >=11 ties at max
  unsigned lo = Emax, hi = Emax;
  if (!done) {
    const unsigned STEP = 1u << 23;  // ~one exponent step for positives
    while (true) {
      hi = lo;
      lo = (lo > STEP) ? (lo - STEP) : 1u;
      c = blk_count(lo);
      if (c >= 11u) break;
      if (lo == 1u) break;  // unreachable for C>=11 real values
    }
    // shrink candidate set if pathologically large; tie-collapse => direct answer
    while (c > CAND_MAX) {
      if (hi - lo <= 1u) { E11 = lo; done = true; break; }
      unsigned mid = lo + ((hi - lo) >> 1);
      unsigned cm = blk_count(mid);
      if (cm >= 11u) { lo = mid; c = cm; } else { hi = mid; }
    }
  }

  // ---- 4. compact candidates (enc >= lo) into LDS, radix-select rank 11 ----
  if (!done) {
    __syncthreads();
    if (tid == 0) sh_sel[0] = 0u;
    __syncthreads();
#pragma unroll
    for (int i = 0; i < NSLOT; ++i) {
      bool pr = (enc[i] >= lo);
      unsigned long long bal = __ballot(pr);
      if (bal) {
        unsigned wcnt = (unsigned)__popcll(bal);
        unsigned basep = 0u;
        if (lane == 0) basep = atomicAdd(&sh_sel[0], wcnt);
        basep = __shfl(basep, 0, 64);
        if (pr) {
          unsigned posn = basep + (unsigned)__popcll(bal & ((1ull << lane) - 1ull));
          sh_cand[posn] = enc[i];
        }
      }
    }
    __syncthreads();

    unsigned prefix = 0u, r = 11u;
    for (int p = 3; p >= 0; --p) {
      sh_hist[tid] = 0u;
      __syncthreads();
      for (unsigned i = tid; i < c; i += 256u) {
        unsigned e = sh_cand[i];
        bool match =
            (p == 3) || ((e >> ((p + 1) * 8)) == (prefix >> ((p + 1) * 8)));
        if (match) atomicAdd(&sh_hist[(e >> (p * 8)) & 255u], 1u);
      }
      __syncthreads();
      if (wid == 0) {
        unsigned b0 = sh_hist[4 * lane + 0], b1 = sh_hist[4 * lane + 1];
        unsigned b2 = sh_hist[4 * lane + 2], b3 = sh_hist[4 * lane + 3];
        unsigned s = b0 + b1 + b2 + b3;
        unsigned t = s;
#pragma unroll
        for (int off = 1; off < 64; off <<= 1) {
          unsigned v = __shfl_down(t, off, 64);
          if (lane + off < 64) t += v;
        }
        unsigned above = t - s;  // count over lanes > L (higher digits)
        unsigned suf3 = above + b3, suf2 = suf3 + b2, suf1 = suf2 + b1,
                 suf0 = suf1 + b0;
        if (suf0 >= r && suf1 < r) { sh_sel[0] = 4u * lane + 0u; sh_sel[1] = r - suf1; }
        if (suf1 >= r && suf2 < r) { sh_sel[0] = 4u * lane + 1u; sh_sel[1] = r - suf2; }
        if (suf2 >= r && suf3 < r) { sh_sel[0] = 4u * lane + 2u; sh_sel[1] = r - suf3; }
        if (suf3 >= r && above < r){ sh_sel[0] = 4u * lane + 3u; sh_sel[1] = r - above; }
      }
      __syncthreads();
      prefix |= sh_sel[0] << (p * 8);
      r = sh_sel[1];
    }
    E11 = prefix;
  }

  // ---- 5. whitelist gather: per-label max, union max, has_pos ----
  __syncthreads();
  const unsigned nu = wsu[0];
  const unsigned* ents = wsu + 4;
  float lm[8];
#pragma unroll
  for (int l = 0; l < 8; ++l) lm[l] = NEGF;
  float um = NEGF;
  unsigned present = 0u, posm = 0u;
  for (unsigned e = tid; e < nu; e += 256u) {
    unsigned ent = ents[e];
    unsigned ccol = ent >> 8;
    unsigned mk = ent & 255u;
    float xv = x[base + (long long)ccol];
    float yv = y[base + (long long)ccol];
    present |= mk;
    if (yv > 0.0f) posm |= mk;
    um = fmaxf(um, xv);
#pragma unroll
    for (int l = 0; l < 8; ++l)
      if ((mk >> l) & 1u) lm[l] = fmaxf(lm[l], xv);
  }
#pragma unroll
  for (int off = 32; off >= 1; off >>= 1) {
    um = fmaxf(um, __shfl_xor(um, off, 64));
    present |= __shfl_xor(present, off, 64);
    posm |= __shfl_xor(posm, off, 64);
#pragma unroll
    for (int l = 0; l < 8; ++l) lm[l] = fmaxf(lm[l], __shfl_xor(lm[l], off, 64));
  }
  if (lane == 0) {
#pragma unroll
    for (int l = 0; l < 8; ++l) sh_wl[wid][l] = lm[l];
    sh_wl[wid][8] = um;
    sh_wl[wid][9] = __uint_as_float(present);
    sh_wl[wid][10] = __uint_as_float(posm);
  }
  __syncthreads();

  // ---- 6. epilogue on thread 0: per-block partial (no global atomics) ----
  if (tid == 0) {
    float LM[8], UM = NEGF;
    unsigned PR = 0u, PO = 0u;
#pragma unroll
    for (int l = 0; l < 8; ++l) LM[l] = NEGF;
    for (int w = 0; w < 4; ++w) {
#pragma unroll
      for (int l = 0; l < 8; ++l) LM[l] = fmaxf(LM[l], sh_wl[w][l]);
      UM = fmaxf(UM, sh_wl[w][8]);
      PR |= __float_as_uint(sh_wl[w][9]);
      PO |= __float_as_uint(sh_wl[w][10]);
    }
    float x11 = dec_u(E11);
    float thres = fmaxf(sigm(x11), 0.5f);
    float cmax = NEGF, imax = NEGF;
#pragma unroll
    for (int l = 0; l < 8; ++l) {
      float ml = ((PR >> l) & 1u) ? sigm(LM[l]) : NEGF;
      if ((PO >> l) & 1u) cmax = fmaxf(cmax, ml);
      else imax = fmaxf(imax, ml);
    }
    bool anyc = (PO != 0u);
    bool anyi = (PO != 255u);  // L == 8 labels, all whitelists non-empty
    float unionmax = (nu > 0u) ? sigm(UM) : NEGF;
    float x1 = anyc ? cmax : thres;
    float x2 = anyc ? (anyi ? fmaxf(imax, thres) : thres) : unionmax;
    float coef = anyc ? 1.0f : 0.5f;
    float dd = x2 - x1 + 0.1f;
    float rank = ((dd > 0.0f) ? 2.0f : 1.0f) * sigm(10.0f * dd);
    partials[b] = coef * rank;
  }
}

__global__ void final_reduce(const float* __restrict__ partials,
                             float* __restrict__ out) {
  __shared__ float sh[4];
  const int tid = threadIdx.x;
  const int lane = tid & 63;
  const int wid = tid >> 6;
  float s = 0.0f;
  for (int i = tid; i < BB; i += 256) s += partials[i];
#pragma unroll
  for (int off = 32; off >= 1; off >>= 1) s += __shfl_xor(s, off, 64);
  if (lane == 0) sh[wid] = s;
  __syncthreads();
  if (tid == 0) out[0] = (sh[0] + sh[1] + sh[2] + sh[3]) * (1.0f / (float)BB);
}

extern "C" void kernel_launch(void* const* d_in, const int* in_sizes, int n_in,
                              void* d_out, int out_size, void* d_ws,
                              size_t ws_size, hipStream_t stream) {
  const float* x = (const float*)d_in[0];
  const float* y = (const float*)d_in[1];
  // d_in[2] (y_neg) is faithfully ignored — it never affects the loss.
  const unsigned char* wl = (const unsigned char*)d_in[3];
  float* out = (float*)d_out;
  unsigned* wsu = (unsigned*)d_ws;
  float* partials = (float*)((char*)d_ws + WS_PARTIALS_OFF);

  hipMemsetAsync(d_ws, 0, 16, stream);  // zero wsu[0..3] (count + flags)
  wl_sniff<<<64, 256, 0, stream>>>(wl, wsu);
  wl_compact<<<(CC + 255) / 256, 256, 0, stream>>>(wl, wsu);
  loss_kernel<<<BB, 256, 0, stream>>>(x, y, wsu, partials);
  final_reduce<<<1, 256, 0, stream>>>(partials, out);
}